// Round 6
// baseline (75.455 us; speedup 1.0000x reference)
//
#include <hip/hip_runtime.h>

#define IMG   512
#define TILE  64
#define HALO  2
#define EXT   (TILE + 2*HALO)   // 68

__global__ __launch_bounds__(256)
void mean_filter_kernel(const float* __restrict__ in, float* __restrict__ out) {
    // raw tile with halo: 68 x 68 (stride 69 to dodge bank conflicts)
    __shared__ float A[EXT][EXT + 1];
    // horizontal 5-sums: 68 rows x 64 cols (stride 65)
    __shared__ float B[EXT][TILE + 1];

    const int plane = blockIdx.z;
    const int tx0 = blockIdx.x * TILE;
    const int ty0 = blockIdx.y * TILE;
    const float* __restrict__ src = in  + (size_t)plane * IMG * IMG;
    float*       __restrict__ dst = out + (size_t)plane * IMG * IMG;
    const int tid = threadIdx.x;

    // Phase 1: cooperative load of the 68x68 halo'd tile (0 outside image
    // => edge-clipped window sum comes out exactly right).
    for (int idx = tid; idx < EXT * EXT; idx += 256) {
        const int r  = idx / EXT;
        const int c  = idx - r * EXT;
        const int gy = ty0 + r - HALO;
        const int gx = tx0 + c - HALO;
        float v = 0.0f;
        if (gy >= 0 && gy < IMG && gx >= 0 && gx < IMG)
            v = src[gy * IMG + gx];
        A[r][c] = v;
    }
    __syncthreads();

    // Phase 2: horizontal 5-wide sums for all 68 rows x 64 output cols.
    for (int idx = tid; idx < EXT * TILE; idx += 256) {
        const int r = idx / TILE;
        const int c = idx - r * TILE;
        B[r][c] = A[r][c] + A[r][c + 1] + A[r][c + 2] + A[r][c + 3] + A[r][c + 4];
    }
    __syncthreads();

    // Phase 3: vertical 5-sum, divide by analytic valid-pixel count, store.
    for (int idx = tid; idx < TILE * TILE; idx += 256) {
        const int y  = idx / TILE;
        const int x  = idx - y * TILE;
        const float s = B[y][x] + B[y + 1][x] + B[y + 2][x] + B[y + 3][x] + B[y + 4][x];
        const int gy = ty0 + y;
        const int gx = tx0 + x;
        const int cy = min(gy + HALO, IMG - 1) - max(gy - HALO, 0) + 1;
        const int cx = min(gx + HALO, IMG - 1) - max(gx - HALO, 0) + 1;
        dst[gy * IMG + gx] = s / (float)(cy * cx);
    }
}

extern "C" void kernel_launch(void* const* d_in, const int* in_sizes, int n_in,
                              void* d_out, int out_size, void* d_ws, size_t ws_size,
                              hipStream_t stream) {
    const float* x = (const float*)d_in[0];
    float* out = (float*)d_out;
    // (32, 3, 512, 512) -> 96 planes of 512x512
    const int planes = in_sizes[0] / (IMG * IMG);   // 96
    dim3 grid(IMG / TILE, IMG / TILE, planes);      // 8 x 8 x 96
    dim3 block(256);
    mean_filter_kernel<<<grid, block, 0, stream>>>(x, out);
}

// Round 7
// 35.815 us; speedup vs baseline: 2.1068x; 2.1068x over previous
//
#include <hip/hip_runtime.h>

#define IMG   512
#define H     16      // output rows per block
#define TPB   128     // threads; each owns 4 consecutive columns (float4)
#define NXCD  8

__global__ __launch_bounds__(TPB)
void mean_filter_strip(const float* __restrict__ in, float* __restrict__ out,
                       int nstrips, int cpx) {
    // double-buffered vertical-sum row: columns -2..513 live at idx 4+c
    // (idx 2,3 = left zeros, 516,517 = right zeros; 16B-aligned float4 at 4+x4)
    __shared__ __align__(16) float vs[2][IMG + 8];

    // bijective XCD-contiguous swizzle (nwg % 8 == 0): adjacent strips -> same XCD
    const int hw  = blockIdx.x;
    const int bid = (hw % NXCD) * cpx + (hw / NXCD);
    const int plane = bid / nstrips;
    const int strip = bid - plane * nstrips;
    const int y0 = strip * H;
    const int x4 = threadIdx.x * 4;

    const float* __restrict__ src = in  + (size_t)plane * IMG * IMG + x4;
    float*       __restrict__ dst = out + (size_t)plane * IMG * IMG + x4;

    // constant zero halos (written once; ordered before first read by the
    // first in-loop __syncthreads)
    if (threadIdx.x < 2) {
        vs[threadIdx.x][2]   = 0.0f;
        vs[threadIdx.x][3]   = 0.0f;
        vs[threadIdx.x][516] = 0.0f;
        vs[threadIdx.x][517] = 0.0f;
    }

    // per-column horizontal reciprocal counts (constant down the strip)
    float invcx[4];
    #pragma unroll
    for (int j = 0; j < 4; ++j) {
        const int x  = x4 + j;
        const int cx = min(x + 2, IMG - 1) - max(x - 2, 0) + 1;
        invcx[j] = 1.0f / (float)cx;
    }

    auto loadrow = [&](int y) -> float4 {
        if ((unsigned)y < (unsigned)IMG)
            return *(const float4*)(src + (size_t)y * IMG);
        return make_float4(0.0f, 0.0f, 0.0f, 0.0f);
    };

    // register ring: rows y-2..y+2 for current output row y
    float4 r0v, r1v, r2v, r3v, r4v;
    r1v = loadrow(y0 - 2);
    r2v = loadrow(y0 - 1);
    r3v = loadrow(y0);
    r4v = loadrow(y0 + 1);

    #pragma unroll
    for (int i = 0; i < H; ++i) {
        const int y = y0 + i;
        r0v = r1v; r1v = r2v; r2v = r3v; r3v = r4v;
        r4v = loadrow(y + 2);

        float4 v;   // vertical 5-sum for own 4 columns
        v.x = r0v.x + r1v.x + r2v.x + r3v.x + r4v.x;
        v.y = r0v.y + r1v.y + r2v.y + r3v.y + r4v.y;
        v.z = r0v.z + r1v.z + r2v.z + r3v.z + r4v.z;
        v.w = r0v.w + r1v.w + r2v.w + r3v.w + r4v.w;

        const int b = i & 1;
        *(float4*)&vs[b][4 + x4] = v;
        __syncthreads();

        // neighbor vertical sums (2 left, 2 right)
        const float l0 = vs[b][x4 + 2];
        const float l1 = vs[b][x4 + 3];
        const float q0 = vs[b][x4 + 8];
        const float q1 = vs[b][x4 + 9];

        const int   cy    = min(y + 2, IMG - 1) - max(y - 2, 0) + 1;
        const float invcy = 1.0f / (float)cy;

        float4 o;
        o.x = (l0 + l1 + v.x + v.y + v.z) * (invcy * invcx[0]);
        o.y = (l1 + v.x + v.y + v.z + v.w) * (invcy * invcx[1]);
        o.z = (v.x + v.y + v.z + v.w + q0) * (invcy * invcx[2]);
        o.w = (v.y + v.z + v.w + q0 + q1) * (invcy * invcx[3]);

        *(float4*)(dst + (size_t)y * IMG) = o;
    }
}

extern "C" void kernel_launch(void* const* d_in, const int* in_sizes, int n_in,
                              void* d_out, int out_size, void* d_ws, size_t ws_size,
                              hipStream_t stream) {
    const float* x = (const float*)d_in[0];
    float* out = (float*)d_out;
    const int planes  = in_sizes[0] / (IMG * IMG);   // 96
    const int nstrips = IMG / H;                     // 32
    const int nwg     = planes * nstrips;            // 3072 (% 8 == 0)
    const int cpx     = nwg / NXCD;                  // 384
    mean_filter_strip<<<dim3(nwg), dim3(TPB), 0, stream>>>(x, out, nstrips, cpx);
}